// Round 10
// baseline (93.302 us; speedup 1.0000x reference)
//
#include <hip/hip_runtime.h>
#include <hip/hip_bf16.h>

#define NN 4096
#define DD 128
#define MARGIN_F 0.3f
#define JC 256                    // columns per block
#define RB 256                    // rows per block (8 waves * 32)
#define GX (NN / JC)              // 16
#define GY (NN / RB)              // 16  -> 256 blocks = 1 per CU
#define NT (JC / 16)              // 16 j-tiles per block

typedef __attribute__((ext_vector_type(8))) short bf16x8;   // 8 bf16 = 4 VGPRs
typedef __attribute__((ext_vector_type(4))) float f32x4;
typedef __attribute__((ext_vector_type(2))) float f32x2;

// Panel-swizzled bf16 layout (ushort units), one 16-row panel = 2048 ushorts:
//   element (row, k) -> (row/16)*2048 + (k/32)*512 + ((k%32)/8)*128
//                       + (row%16)*8 + (k%8)
// A fragment load (lane = quad*16+col16) is one coalesced 1KB transaction,
// and a whole 16-row panel is a CONTIGUOUS 4KB block -> global_load_lds-able.
//
// ws layout:
//   [0 .. 1MB)   p1t (swizzled bf16)
//   [1MB .. 2MB) p2t
//   then fp32:   a2[N], b2[N], c[N], rowmax[N] (uint), sumpart[16]

__device__ __forceinline__ ushort f2bf(float f) {
  __hip_bfloat16 h = __float2bfloat16(f);   // RNE
  return *reinterpret_cast<ushort*>(&h);
}

// async global->LDS, 16B per lane; lds dest = wave-uniform base + lane*16
__device__ __forceinline__ void gload_lds16(const ushort* g, ushort* l) {
  __builtin_amdgcn_global_load_lds(
      (const __attribute__((address_space(1))) void*)g,
      (__attribute__((address_space(3))) void*)l, 16, 0, 0);
}

// Fused: bf16 convert+swizzle + row stats + workspace init. One wave per row.
__global__ __launch_bounds__(256) void ptl_prep(
    const float* __restrict__ p1, const float* __restrict__ p2,
    ushort* __restrict__ p1t, ushort* __restrict__ p2t,
    float* __restrict__ a2, float* __restrict__ b2, float* __restrict__ c,
    unsigned int* __restrict__ rowmax, float* __restrict__ sumpart) {
  int row = blockIdx.x * 4 + (threadIdx.x >> 6);
  int lane = threadIdx.x & 63;
  float2 x = ((const float2*)(p1 + (size_t)row * DD))[lane];
  float2 y = ((const float2*)(p2 + (size_t)row * DD))[lane];
  ushort2 xb, yb;
  xb.x = f2bf(x.x); xb.y = f2bf(x.y);
  yb.x = f2bf(y.x); yb.y = f2bf(y.y);
  int k = lane * 2;
  size_t idx = (size_t)(row >> 4) * 2048 + (size_t)(k >> 5) * 512 +
               (size_t)((k & 31) >> 3) * 128 + (size_t)(row & 15) * 8 +
               (size_t)(k & 7);
  *(ushort2*)(p1t + idx) = xb;
  *(ushort2*)(p2t + idx) = yb;

  float sa = x.x * x.x + x.y * x.y;
  float sb = y.x * y.x + y.y * y.y;
  float d0 = x.x - y.x, d1 = x.y - y.y;
  float sd = d0 * d0 + d1 * d1;
#pragma unroll
  for (int off = 32; off > 0; off >>= 1) {
    sa += __shfl_down(sa, off);
    sb += __shfl_down(sb, off);
    sd += __shfl_down(sd, off);
  }
  if (lane == 0) {
    a2[row] = sa;
    b2[row] = sb;
    c[row] = sd - sa + MARGIN_F;   // dist_ap - ||p1_i||^2 + margin
    rowmax[row] = 0u;              // uint bits of nonneg float
  }
  if (blockIdx.x == 0 && threadIdx.x < 16) sumpart[threadIdx.x] = 0.f;
}

// 256x256 tile, 8 waves, 1 block/CU, single round. ALL 32 B panels (128KB)
// bulk-staged via async global_load_lds, ONE barrier, 16 j-tiles of
// barrier-free LDS->MFMA->epilogue. Clean exit (no fence/ticket).
// C layout: col = lane&15, row = quad*4 + reg.
__global__ __launch_bounds__(512) void ptl_mfma(
    const ushort* __restrict__ p1t, const ushort* __restrict__ p2t,
    const float* __restrict__ a2v, const float* __restrict__ b2v,
    const float* __restrict__ cvv, unsigned int* __restrict__ rowmax,
    float* __restrict__ sumpart) {
  const int tid = threadIdx.x;
  const int w = tid >> 6;           // 0..7
  const int lane = tid & 63;
  const int col16 = lane & 15;
  const int quad = lane >> 4;
  const int rowBase = blockIdx.y * RB + w * 32;
  const int jBase = blockIdx.x * JC;
  const int lofs = quad * 128 + col16 * 8;   // ushort offset within a panel

  __shared__ __align__(16) ushort ldsB[2][NT][2048];  // [arr][panel] = 128KB
  __shared__ float wsum[8];

  // Bulk stage: wave w covers panels {2w, 2w+1} of both arrays (16KB/wave).
  {
    const int p0 = w * 2;
#pragma unroll
    for (int arr = 0; arr < 2; ++arr) {
      const ushort* gsrc = (arr ? p2t : p1t) +
                           (size_t)((jBase >> 4) + p0) * 2048 + lane * 8;
#pragma unroll
      for (int pp = 0; pp < 2; ++pp)
#pragma unroll
        for (int ch = 0; ch < 4; ++ch)
          gload_lds16(gsrc + pp * 2048 + ch * 512,
                      &ldsB[arr][p0 + pp][ch * 512 + lane * 8]);
    }
  }

  // A fragments, both strips, full K — coalesced panel loads from global
  bf16x8 afr[2][4];
#pragma unroll
  for (int st = 0; st < 2; ++st) {
    const ushort* pa = p1t + ((size_t)(rowBase >> 4) + st) * 2048 + lofs;
#pragma unroll
    for (int s = 0; s < 4; ++s) afr[st][s] = *(const bf16x8*)(pa + s * 512);
  }

  float cv[2][4];
#pragma unroll
  for (int st = 0; st < 2; ++st)
#pragma unroll
    for (int r = 0; r < 4; ++r) cv[st][r] = cvv[rowBase + st * 16 + quad * 4 + r];

  f32x2 lsum2 = {0.f, 0.f};
  f32x2 rmax2[2][4];
#pragma unroll
  for (int st = 0; st < 2; ++st)
#pragma unroll
    for (int r = 0; r < 4; ++r) rmax2[st][r] = (f32x2){0.f, 0.f};

  __syncthreads();   // single barrier: all 128KB of B staged, A frags resident

#pragma unroll
  for (int jt = 0; jt < NT; ++jt) {
    bf16x8 b1[4], b2[4];
#pragma unroll
    for (int s = 0; s < 4; ++s) {
      b1[s] = *(const bf16x8*)&ldsB[0][jt][s * 512 + lofs];
      b2[s] = *(const bf16x8*)&ldsB[1][jt][s * 512 + lofs];
    }
    f32x4 acc[2][2];
#pragma unroll
    for (int st = 0; st < 2; ++st)
#pragma unroll
      for (int m = 0; m < 2; ++m) acc[st][m] = (f32x4){0.f, 0.f, 0.f, 0.f};
#pragma unroll
    for (int s = 0; s < 4; ++s) {
      acc[0][0] = __builtin_amdgcn_mfma_f32_16x16x32_bf16(afr[0][s], b1[s], acc[0][0], 0, 0, 0);
      acc[1][0] = __builtin_amdgcn_mfma_f32_16x16x32_bf16(afr[1][s], b1[s], acc[1][0], 0, 0, 0);
      acc[0][1] = __builtin_amdgcn_mfma_f32_16x16x32_bf16(afr[0][s], b2[s], acc[0][1], 0, 0, 0);
      acc[1][1] = __builtin_amdgcn_mfma_f32_16x16x32_bf16(afr[1][s], b2[s], acc[1][1], 0, 0, 0);
    }

    const int jcol = jBase + jt * 16 + col16;
    f32x2 nj = { a2v[jcol], b2v[jcol] };
#pragma unroll
    for (int st = 0; st < 2; ++st) {
      const bool diagT = (jBase + jt * 16) == (rowBase + st * 16);
#pragma unroll
      for (int r = 0; r < 4; ++r) {
        f32x2 t = { acc[st][0][r], acc[st][1][r] };
        f32x2 v = t * 2.f + (cv[st][r] - nj);
        v.x = fmaxf(v.x, 0.f);
        v.y = fmaxf(v.y, 0.f);
        if (diagT && col16 == quad * 4 + r) v = (f32x2){0.f, 0.f};
        lsum2 += v;
        rmax2[st][r].x = fmaxf(rmax2[st][r].x, v.x);
        rmax2[st][r].y = fmaxf(rmax2[st][r].y, v.y);
      }
    }
  }

  float lsum = lsum2.x + lsum2.y;
  float rmax[2][4];
#pragma unroll
  for (int st = 0; st < 2; ++st)
#pragma unroll
    for (int r = 0; r < 4; ++r)
      rmax[st][r] = fmaxf(rmax2[st][r].x, rmax2[st][r].y);

  // row-max across the 16 col lanes of each quad (xor<16 stays in-group)
#pragma unroll
  for (int off = 8; off > 0; off >>= 1)
#pragma unroll
    for (int st = 0; st < 2; ++st)
#pragma unroll
      for (int r = 0; r < 4; ++r)
        rmax[st][r] = fmaxf(rmax[st][r], __shfl_xor(rmax[st][r], off));
  if (col16 == 0) {
#pragma unroll
    for (int st = 0; st < 2; ++st)
#pragma unroll
      for (int r = 0; r < 4; ++r)
        atomicMax(&rowmax[rowBase + st * 16 + quad * 4 + r],
                  __float_as_uint(rmax[st][r]));
  }

  // block sum -> 16 distributed accumulator slots
#pragma unroll
  for (int off = 32; off > 0; off >>= 1) lsum += __shfl_down(lsum, off);
  if (lane == 0) wsum[w] = lsum;
  __syncthreads();
  if (tid == 0) {
    float s = 0.f;
#pragma unroll
    for (int i = 0; i < 8; ++i) s += wsum[i];
    const int bid = blockIdx.y * GX + blockIdx.x;
    atomicAdd(&sumpart[bid & 15], s);
  }
}

// Separate finalize: kernel boundary is a full device memory sync -> plain loads.
__global__ __launch_bounds__(256) void ptl_fin(
    const unsigned int* __restrict__ rowmax, const float* __restrict__ sumpart,
    float* __restrict__ out) {
  float sm = 0.f;
#pragma unroll
  for (int it = 0; it < 4; ++it) {
    uint4 u = ((const uint4*)rowmax)[it * 256 + threadIdx.x];
    sm += __uint_as_float(u.x) + __uint_as_float(u.y) +
          __uint_as_float(u.z) + __uint_as_float(u.w);
  }
#pragma unroll
  for (int off = 32; off > 0; off >>= 1) sm += __shfl_down(sm, off);
  __shared__ float wm[4];
  if ((threadIdx.x & 63) == 0) wm[threadIdx.x >> 6] = sm;
  __syncthreads();
  if (threadIdx.x == 0) {
    float sp = 0.f;
#pragma unroll
    for (int i = 0; i < 16; ++i) sp += sumpart[i];
    out[0] = (wm[0] + wm[1] + wm[2] + wm[3]) / (float)NN;
    out[1] = sp / (2.0f * (float)NN * (float)(NN - 1));
  }
}

extern "C" void kernel_launch(void* const* d_in, const int* in_sizes, int n_in,
                              void* d_out, int out_size, void* d_ws, size_t ws_size,
                              hipStream_t stream) {
  const float* p1 = (const float*)d_in[0];
  const float* p2 = (const float*)d_in[1];
  ushort* p1t = (ushort*)d_ws;
  ushort* p2t = p1t + (size_t)NN * DD;
  float* a2 = (float*)(p2t + (size_t)NN * DD);
  float* b2 = a2 + NN;
  float* c = b2 + NN;
  unsigned int* rowmax = (unsigned int*)(c + NN);
  float* sumpart = (float*)(rowmax + NN);

  ptl_prep<<<NN / 4, 256, 0, stream>>>(p1, p2, p1t, p2t, a2, b2, c,
                                       rowmax, sumpart);

  dim3 grid(GX, GY);  // (16, 16) = 256 blocks = 1 per CU
  ptl_mfma<<<grid, 512, 0, stream>>>(p1t, p2t, a2, b2, c, rowmax, sumpart);

  ptl_fin<<<1, 256, 0, stream>>>(rowmax, sumpart, (float*)d_out);
}

// Round 12
// 80.330 us; speedup vs baseline: 1.1615x; 1.1615x over previous
//
#include <hip/hip_runtime.h>
#include <hip/hip_bf16.h>

#define NN 4096
#define DD 128
#define MARGIN_F 0.3f
#define JC 128                    // columns per block
#define RB 256                    // rows per block (8 waves * 32)
#define GX (NN / JC)              // 32
#define GY (NN / RB)              // 16  -> 512 blocks, 2 per CU
#define NT (JC / 16)              // 8 j-tiles per block

typedef __attribute__((ext_vector_type(8))) short bf16x8;   // 8 bf16 = 4 VGPRs
typedef __attribute__((ext_vector_type(4))) float f32x4;
typedef __attribute__((ext_vector_type(2))) float f32x2;

// Panel-swizzled bf16 layout (ushort units), one 16-row panel = 2048 ushorts:
//   element (row, k) -> (row/16)*2048 + (k/32)*512 + ((k%32)/8)*128
//                       + (row%16)*8 + (k%8)
// A fragment load (lane = quad*16+col16) is one coalesced 1KB transaction,
// and a whole 16-row panel is a CONTIGUOUS 4KB block -> global_load_lds-able.
//
// ws layout:
//   [0 .. 1MB)   p1t (swizzled bf16)
//   [1MB .. 2MB) p2t
//   then fp32:   a2[N], b2[N], c[N], rowmax[N] (uint), sumpart[16]

__device__ __forceinline__ ushort f2bf(float f) {
  __hip_bfloat16 h = __float2bfloat16(f);   // RNE
  return *reinterpret_cast<ushort*>(&h);
}

// async global->LDS, 16B per lane; lds dest = wave-uniform base + lane*16
__device__ __forceinline__ void gload_lds16(const ushort* g, ushort* l) {
  __builtin_amdgcn_global_load_lds(
      (const __attribute__((address_space(1))) void*)g,
      (__attribute__((address_space(3))) void*)l, 16, 0, 0);
}

// Fused: bf16 convert+swizzle + row stats + workspace init. One wave per row.
__global__ __launch_bounds__(256) void ptl_prep(
    const float* __restrict__ p1, const float* __restrict__ p2,
    ushort* __restrict__ p1t, ushort* __restrict__ p2t,
    float* __restrict__ a2, float* __restrict__ b2, float* __restrict__ c,
    unsigned int* __restrict__ rowmax, float* __restrict__ sumpart) {
  int row = blockIdx.x * 4 + (threadIdx.x >> 6);
  int lane = threadIdx.x & 63;
  float2 x = ((const float2*)(p1 + (size_t)row * DD))[lane];
  float2 y = ((const float2*)(p2 + (size_t)row * DD))[lane];
  ushort2 xb, yb;
  xb.x = f2bf(x.x); xb.y = f2bf(x.y);
  yb.x = f2bf(y.x); yb.y = f2bf(y.y);
  int k = lane * 2;
  size_t idx = (size_t)(row >> 4) * 2048 + (size_t)(k >> 5) * 512 +
               (size_t)((k & 31) >> 3) * 128 + (size_t)(row & 15) * 8 +
               (size_t)(k & 7);
  *(ushort2*)(p1t + idx) = xb;
  *(ushort2*)(p2t + idx) = yb;

  float sa = x.x * x.x + x.y * x.y;
  float sb = y.x * y.x + y.y * y.y;
  float d0 = x.x - y.x, d1 = x.y - y.y;
  float sd = d0 * d0 + d1 * d1;
#pragma unroll
  for (int off = 32; off > 0; off >>= 1) {
    sa += __shfl_down(sa, off);
    sb += __shfl_down(sb, off);
    sd += __shfl_down(sd, off);
  }
  if (lane == 0) {
    a2[row] = sa;
    b2[row] = sb;
    c[row] = sd - sa + MARGIN_F;   // dist_ap - ||p1_i||^2 + margin
    rowmax[row] = 0u;              // uint bits of nonneg float
  }
  if (blockIdx.x == 0 && threadIdx.x < 16) sumpart[threadIdx.x] = 0.f;
}

// MFMA sweep: 256 rows x 128 cols per block (8 waves x 32 rows). B-tiles
// staged in LDS (shared by 8 waves), double-buffered async global_load_lds
// (1 instr/wave/tile); A fragments from global (coalesced panel loads).
// Clean exit (no fence/ticket). C layout: col=lane&15, row=quad*4+reg.
__global__ __launch_bounds__(512) void ptl_mfma(
    const ushort* __restrict__ p1t, const ushort* __restrict__ p2t,
    const float* __restrict__ a2v, const float* __restrict__ b2v,
    const float* __restrict__ cvv, unsigned int* __restrict__ rowmax,
    float* __restrict__ sumpart) {
  const int tid = threadIdx.x;
  const int w = tid >> 6;           // 0..7
  const int lane = tid & 63;
  const int col16 = lane & 15;
  const int quad = lane >> 4;
  const int rowBase = blockIdx.y * RB + w * 32;
  const int jBase = blockIdx.x * JC;
  const int lofs = quad * 128 + col16 * 8;   // ushort offset within a panel

  __shared__ __align__(16) ushort ldsB[2][2][2048];  // [stage][arr][panel] 16KB
  __shared__ float wsum[8];

  // B prefetch: wave w stages 1KB of the 8KB (b1,b2) panel pair per tile.
  const int arr = w >> 2;    // 0 -> p1t panel, 1 -> p2t panel
  const int qtr = w & 3;     // quarter of the 4KB panel
  const ushort* gB = (arr ? p2t : p1t) + (size_t)(jBase >> 4) * 2048 +
                     qtr * 512 + lane * 8;
  ushort* lB0 = &ldsB[0][arr][qtr * 512 + lane * 8];
  ushort* lB1 = &ldsB[1][arr][qtr * 512 + lane * 8];

  // issue tile 0 prefetch immediately
  gload_lds16(gB, lB0);

  // A fragments, both strips, full K — coalesced panel loads from global
  bf16x8 afr[2][4];
#pragma unroll
  for (int st = 0; st < 2; ++st) {
    const ushort* pa = p1t + ((size_t)(rowBase >> 4) + st) * 2048 + lofs;
#pragma unroll
    for (int s = 0; s < 4; ++s) afr[st][s] = *(const bf16x8*)(pa + s * 512);
  }

  float cv[2][4];
#pragma unroll
  for (int st = 0; st < 2; ++st)
#pragma unroll
    for (int r = 0; r < 4; ++r) cv[st][r] = cvv[rowBase + st * 16 + quad * 4 + r];

  f32x2 lsum2 = {0.f, 0.f};
  f32x2 rmax2[2][4];
#pragma unroll
  for (int st = 0; st < 2; ++st)
#pragma unroll
    for (int r = 0; r < 4; ++r) rmax2[st][r] = (f32x2){0.f, 0.f};

#pragma unroll
  for (int jt = 0; jt < NT; ++jt) {
    const int cur = jt & 1;
    __syncthreads();   // ldsB[cur] filled (vmcnt drained); ldsB[1-cur] free
    if (jt + 1 < NT)
      gload_lds16(gB + (size_t)(jt + 1) * 2048, cur ? lB0 : lB1);

    bf16x8 b1[4], b2[4];
#pragma unroll
    for (int s = 0; s < 4; ++s) {
      b1[s] = *(const bf16x8*)&ldsB[cur][0][s * 512 + lofs];
      b2[s] = *(const bf16x8*)&ldsB[cur][1][s * 512 + lofs];
    }
    f32x4 acc[2][2];
#pragma unroll
    for (int st = 0; st < 2; ++st)
#pragma unroll
      for (int m = 0; m < 2; ++m) acc[st][m] = (f32x4){0.f, 0.f, 0.f, 0.f};
#pragma unroll
    for (int s = 0; s < 4; ++s) {
      acc[0][0] = __builtin_amdgcn_mfma_f32_16x16x32_bf16(afr[0][s], b1[s], acc[0][0], 0, 0, 0);
      acc[1][0] = __builtin_amdgcn_mfma_f32_16x16x32_bf16(afr[1][s], b1[s], acc[1][0], 0, 0, 0);
      acc[0][1] = __builtin_amdgcn_mfma_f32_16x16x32_bf16(afr[0][s], b2[s], acc[0][1], 0, 0, 0);
      acc[1][1] = __builtin_amdgcn_mfma_f32_16x16x32_bf16(afr[1][s], b2[s], acc[1][1], 0, 0, 0);
    }

    const int jcol = jBase + jt * 16 + col16;
    f32x2 nj = { a2v[jcol], b2v[jcol] };
#pragma unroll
    for (int st = 0; st < 2; ++st) {
      const bool diagT = (jBase + jt * 16) == (rowBase + st * 16);
#pragma unroll
      for (int r = 0; r < 4; ++r) {
        f32x2 t = { acc[st][0][r], acc[st][1][r] };
        f32x2 v = t * 2.f + (cv[st][r] - nj);
        v.x = fmaxf(v.x, 0.f);
        v.y = fmaxf(v.y, 0.f);
        if (diagT && col16 == quad * 4 + r) v = (f32x2){0.f, 0.f};
        lsum2 += v;
        rmax2[st][r].x = fmaxf(rmax2[st][r].x, v.x);
        rmax2[st][r].y = fmaxf(rmax2[st][r].y, v.y);
      }
    }
  }

  float lsum = lsum2.x + lsum2.y;
  float rmax[2][4];
#pragma unroll
  for (int st = 0; st < 2; ++st)
#pragma unroll
    for (int r = 0; r < 4; ++r)
      rmax[st][r] = fmaxf(rmax2[st][r].x, rmax2[st][r].y);

  // row-max across the 16 col lanes of each quad (xor<16 stays in-group)
#pragma unroll
  for (int off = 8; off > 0; off >>= 1)
#pragma unroll
    for (int st = 0; st < 2; ++st)
#pragma unroll
      for (int r = 0; r < 4; ++r)
        rmax[st][r] = fmaxf(rmax[st][r], __shfl_xor(rmax[st][r], off));
  if (col16 == 0) {
#pragma unroll
    for (int st = 0; st < 2; ++st)
#pragma unroll
      for (int r = 0; r < 4; ++r)
        atomicMax(&rowmax[rowBase + st * 16 + quad * 4 + r],
                  __float_as_uint(rmax[st][r]));
  }

  // block sum -> 16 distributed accumulator slots
#pragma unroll
  for (int off = 32; off > 0; off >>= 1) lsum += __shfl_down(lsum, off);
  if (lane == 0) wsum[w] = lsum;
  __syncthreads();
  if (tid == 0) {
    float s = 0.f;
#pragma unroll
    for (int i = 0; i < 8; ++i) s += wsum[i];
    const int bid = blockIdx.y * GX + blockIdx.x;
    atomicAdd(&sumpart[bid & 15], s);
  }
}

// Separate finalize: kernel boundary is a full device memory sync -> plain loads.
__global__ __launch_bounds__(256) void ptl_fin(
    const unsigned int* __restrict__ rowmax, const float* __restrict__ sumpart,
    float* __restrict__ out) {
  float sm = 0.f;
#pragma unroll
  for (int it = 0; it < 4; ++it) {
    uint4 u = ((const uint4*)rowmax)[it * 256 + threadIdx.x];
    sm += __uint_as_float(u.x) + __uint_as_float(u.y) +
          __uint_as_float(u.z) + __uint_as_float(u.w);
  }
#pragma unroll
  for (int off = 32; off > 0; off >>= 1) sm += __shfl_down(sm, off);
  __shared__ float wm[4];
  if ((threadIdx.x & 63) == 0) wm[threadIdx.x >> 6] = sm;
  __syncthreads();
  if (threadIdx.x == 0) {
    float sp = 0.f;
#pragma unroll
    for (int i = 0; i < 16; ++i) sp += sumpart[i];
    out[0] = (wm[0] + wm[1] + wm[2] + wm[3]) / (float)NN;
    out[1] = sp / (2.0f * (float)NN * (float)(NN - 1));
  }
}

extern "C" void kernel_launch(void* const* d_in, const int* in_sizes, int n_in,
                              void* d_out, int out_size, void* d_ws, size_t ws_size,
                              hipStream_t stream) {
  const float* p1 = (const float*)d_in[0];
  const float* p2 = (const float*)d_in[1];
  ushort* p1t = (ushort*)d_ws;
  ushort* p2t = p1t + (size_t)NN * DD;
  float* a2 = (float*)(p2t + (size_t)NN * DD);
  float* b2 = a2 + NN;
  float* c = b2 + NN;
  unsigned int* rowmax = (unsigned int*)(c + NN);
  float* sumpart = (float*)(rowmax + NN);

  ptl_prep<<<NN / 4, 256, 0, stream>>>(p1, p2, p1t, p2t, a2, b2, c,
                                       rowmax, sumpart);

  dim3 grid(GX, GY);  // (32, 16) = 512 blocks, 2 per CU
  ptl_mfma<<<grid, 512, 0, stream>>>(p1t, p2t, a2, b2, c, rowmax, sumpart);

  ptl_fin<<<1, 256, 0, stream>>>(rowmax, sumpart, (float*)d_out);
}

// Round 13
// 78.453 us; speedup vs baseline: 1.1893x; 1.0239x over previous
//
#include <hip/hip_runtime.h>
#include <hip/hip_bf16.h>

#define NN 4096
#define DD 128
#define MARGIN_F 0.3f
#define JC 128                    // columns per block
#define RB 256                    // rows per block (8 waves * 32)
#define GX (NN / JC)              // 32
#define GY (NN / RB)              // 16  -> 512 blocks, 2 per CU
#define NT (JC / 16)              // 8 j-tiles per block

typedef __attribute__((ext_vector_type(8))) short bf16x8;   // 8 bf16 = 4 VGPRs
typedef __attribute__((ext_vector_type(4))) float f32x4;
typedef __attribute__((ext_vector_type(2))) float f32x2;

// Panel-swizzled bf16 layout (ushort units), one 16-row panel = 2048 ushorts:
//   element (row, k) -> (row/16)*2048 + (k/32)*512 + ((k%32)/8)*128
//                       + (row%16)*8 + (k%8)
// A fragment load (lane = quad*16+col16) is one coalesced 1KB transaction.
//
// ws layout:
//   [0 .. 1MB)   p1t (swizzled bf16)
//   [1MB .. 2MB) p2t
//   then fp32:   a2[N], b2[N], c[N], rowmax[N] (uint), sumpart[16]

__device__ __forceinline__ ushort f2bf(float f) {
  __hip_bfloat16 h = __float2bfloat16(f);   // RNE
  return *reinterpret_cast<ushort*>(&h);
}

// Fused: bf16 convert+swizzle + row stats + workspace init. One wave per row.
__global__ __launch_bounds__(256) void ptl_prep(
    const float* __restrict__ p1, const float* __restrict__ p2,
    ushort* __restrict__ p1t, ushort* __restrict__ p2t,
    float* __restrict__ a2, float* __restrict__ b2, float* __restrict__ c,
    unsigned int* __restrict__ rowmax, float* __restrict__ sumpart) {
  int row = blockIdx.x * 4 + (threadIdx.x >> 6);
  int lane = threadIdx.x & 63;
  float2 x = ((const float2*)(p1 + (size_t)row * DD))[lane];
  float2 y = ((const float2*)(p2 + (size_t)row * DD))[lane];
  ushort2 xb, yb;
  xb.x = f2bf(x.x); xb.y = f2bf(x.y);
  yb.x = f2bf(y.x); yb.y = f2bf(y.y);
  int k = lane * 2;
  size_t idx = (size_t)(row >> 4) * 2048 + (size_t)(k >> 5) * 512 +
               (size_t)((k & 31) >> 3) * 128 + (size_t)(row & 15) * 8 +
               (size_t)(k & 7);
  *(ushort2*)(p1t + idx) = xb;
  *(ushort2*)(p2t + idx) = yb;

  float sa = x.x * x.x + x.y * x.y;
  float sb = y.x * y.x + y.y * y.y;
  float d0 = x.x - y.x, d1 = x.y - y.y;
  float sd = d0 * d0 + d1 * d1;
#pragma unroll
  for (int off = 32; off > 0; off >>= 1) {
    sa += __shfl_down(sa, off);
    sb += __shfl_down(sb, off);
    sd += __shfl_down(sd, off);
  }
  if (lane == 0) {
    a2[row] = sa;
    b2[row] = sb;
    c[row] = sd - sa + MARGIN_F;   // dist_ap - ||p1_i||^2 + margin
    rowmax[row] = 0u;              // uint bits of nonneg float
  }
  if (blockIdx.x == 0 && threadIdx.x < 16) sumpart[threadIdx.x] = 0.f;
}

// MFMA sweep: 256 rows x 128 cols per block (8 waves x 32 rows). B-tiles
// staged in LDS via PLAIN global load -> VGPR -> ds_write_b128 (full-rate
// paths; global_load_lds DMA ingest measured slow R6-R12), double-buffered:
// load tile jt+1 into a register while computing jt, write before barrier.
// Clean exit (no fence/ticket). C layout: col=lane&15, row=quad*4+reg.
__global__ __launch_bounds__(512) void ptl_mfma(
    const ushort* __restrict__ p1t, const ushort* __restrict__ p2t,
    const float* __restrict__ a2v, const float* __restrict__ b2v,
    const float* __restrict__ cvv, unsigned int* __restrict__ rowmax,
    float* __restrict__ sumpart) {
  const int tid = threadIdx.x;
  const int w = tid >> 6;           // 0..7
  const int lane = tid & 63;
  const int col16 = lane & 15;
  const int quad = lane >> 4;
  const int rowBase = blockIdx.y * RB + w * 32;
  const int jBase = blockIdx.x * JC;
  const int lofs = quad * 128 + col16 * 8;   // ushort offset within a panel

  __shared__ __align__(16) ushort ldsB[2][2][2048];  // [stage][arr][panel] 16KB
  __shared__ float wsum[8];

  // B staging: wave w covers 1KB of the 8KB (b1,b2) panel pair per tile.
  const int arr = w >> 2;    // 0 -> p1t panel, 1 -> p2t panel
  const int qtr = w & 3;     // quarter of the 4KB panel
  const ushort* gB = (arr ? p2t : p1t) + (size_t)(jBase >> 4) * 2048 +
                     qtr * 512 + lane * 8;
  ushort* lW0 = &ldsB[0][arr][qtr * 512 + lane * 8];
  ushort* lW1 = &ldsB[1][arr][qtr * 512 + lane * 8];

  // tile 0 stage via register (plain load, full-rate path)
  bf16x8 stg = *(const bf16x8*)gB;

  // A fragments, both strips, full K — coalesced panel loads from global
  bf16x8 afr[2][4];
#pragma unroll
  for (int st = 0; st < 2; ++st) {
    const ushort* pa = p1t + ((size_t)(rowBase >> 4) + st) * 2048 + lofs;
#pragma unroll
    for (int s = 0; s < 4; ++s) afr[st][s] = *(const bf16x8*)(pa + s * 512);
  }

  float cv[2][4];
#pragma unroll
  for (int st = 0; st < 2; ++st)
#pragma unroll
    for (int r = 0; r < 4; ++r) cv[st][r] = cvv[rowBase + st * 16 + quad * 4 + r];

  *(bf16x8*)lW0 = stg;   // tile 0 -> LDS[0]

  f32x2 lsum2 = {0.f, 0.f};
  f32x2 rmax2[2][4];
#pragma unroll
  for (int st = 0; st < 2; ++st)
#pragma unroll
    for (int r = 0; r < 4; ++r) rmax2[st][r] = (f32x2){0.f, 0.f};

#pragma unroll
  for (int jt = 0; jt < NT; ++jt) {
    const int cur = jt & 1;
    __syncthreads();   // LDS[cur] writes visible; LDS[1-cur] fully consumed

    // prefetch tile jt+1 into a register (latency hidden by MFMA+epilogue)
    bf16x8 stgN;
    if (jt + 1 < NT) stgN = *(const bf16x8*)(gB + (size_t)(jt + 1) * 2048);

    bf16x8 b1[4], b2[4];
#pragma unroll
    for (int s = 0; s < 4; ++s) {
      b1[s] = *(const bf16x8*)&ldsB[cur][0][s * 512 + lofs];
      b2[s] = *(const bf16x8*)&ldsB[cur][1][s * 512 + lofs];
    }
    f32x4 acc[2][2];
#pragma unroll
    for (int st = 0; st < 2; ++st)
#pragma unroll
      for (int m = 0; m < 2; ++m) acc[st][m] = (f32x4){0.f, 0.f, 0.f, 0.f};
#pragma unroll
    for (int s = 0; s < 4; ++s) {
      acc[0][0] = __builtin_amdgcn_mfma_f32_16x16x32_bf16(afr[0][s], b1[s], acc[0][0], 0, 0, 0);
      acc[1][0] = __builtin_amdgcn_mfma_f32_16x16x32_bf16(afr[1][s], b1[s], acc[1][0], 0, 0, 0);
      acc[0][1] = __builtin_amdgcn_mfma_f32_16x16x32_bf16(afr[0][s], b2[s], acc[0][1], 0, 0, 0);
      acc[1][1] = __builtin_amdgcn_mfma_f32_16x16x32_bf16(afr[1][s], b2[s], acc[1][1], 0, 0, 0);
    }

    const int jcol = jBase + jt * 16 + col16;
    f32x2 nj = { a2v[jcol], b2v[jcol] };
#pragma unroll
    for (int st = 0; st < 2; ++st) {
      const bool diagT = (jBase + jt * 16) == (rowBase + st * 16);
#pragma unroll
      for (int r = 0; r < 4; ++r) {
        f32x2 t = { acc[st][0][r], acc[st][1][r] };
        f32x2 v = t * 2.f + (cv[st][r] - nj);
        v.x = fmaxf(v.x, 0.f);
        v.y = fmaxf(v.y, 0.f);
        if (diagT && col16 == quad * 4 + r) v = (f32x2){0.f, 0.f};
        lsum2 += v;
        rmax2[st][r].x = fmaxf(rmax2[st][r].x, v.x);
        rmax2[st][r].y = fmaxf(rmax2[st][r].y, v.y);
      }
    }

    // write tile jt+1 into the other buffer (safe: consumed 1 iter ago)
    if (jt + 1 < NT) *(bf16x8*)(cur ? lW0 : lW1) = stgN;
  }

  float lsum = lsum2.x + lsum2.y;
  float rmax[2][4];
#pragma unroll
  for (int st = 0; st < 2; ++st)
#pragma unroll
    for (int r = 0; r < 4; ++r)
      rmax[st][r] = fmaxf(rmax2[st][r].x, rmax2[st][r].y);

  // row-max across the 16 col lanes of each quad (xor<16 stays in-group)
#pragma unroll
  for (int off = 8; off > 0; off >>= 1)
#pragma unroll
    for (int st = 0; st < 2; ++st)
#pragma unroll
      for (int r = 0; r < 4; ++r)
        rmax[st][r] = fmaxf(rmax[st][r], __shfl_xor(rmax[st][r], off));
  if (col16 == 0) {
#pragma unroll
    for (int st = 0; st < 2; ++st)
#pragma unroll
      for (int r = 0; r < 4; ++r)
        atomicMax(&rowmax[rowBase + st * 16 + quad * 4 + r],
                  __float_as_uint(rmax[st][r]));
  }

  // block sum -> 16 distributed accumulator slots
#pragma unroll
  for (int off = 32; off > 0; off >>= 1) lsum += __shfl_down(lsum, off);
  if (lane == 0) wsum[w] = lsum;
  __syncthreads();
  if (tid == 0) {
    float s = 0.f;
#pragma unroll
    for (int i = 0; i < 8; ++i) s += wsum[i];
    const int bid = blockIdx.y * GX + blockIdx.x;
    atomicAdd(&sumpart[bid & 15], s);
  }
}

// Separate finalize: kernel boundary is a full device memory sync -> plain loads.
__global__ __launch_bounds__(256) void ptl_fin(
    const unsigned int* __restrict__ rowmax, const float* __restrict__ sumpart,
    float* __restrict__ out) {
  float sm = 0.f;
#pragma unroll
  for (int it = 0; it < 4; ++it) {
    uint4 u = ((const uint4*)rowmax)[it * 256 + threadIdx.x];
    sm += __uint_as_float(u.x) + __uint_as_float(u.y) +
          __uint_as_float(u.z) + __uint_as_float(u.w);
  }
#pragma unroll
  for (int off = 32; off > 0; off >>= 1) sm += __shfl_down(sm, off);
  __shared__ float wm[4];
  if ((threadIdx.x & 63) == 0) wm[threadIdx.x >> 6] = sm;
  __syncthreads();
  if (threadIdx.x == 0) {
    float sp = 0.f;
#pragma unroll
    for (int i = 0; i < 16; ++i) sp += sumpart[i];
    out[0] = (wm[0] + wm[1] + wm[2] + wm[3]) / (float)NN;
    out[1] = sp / (2.0f * (float)NN * (float)(NN - 1));
  }
}

extern "C" void kernel_launch(void* const* d_in, const int* in_sizes, int n_in,
                              void* d_out, int out_size, void* d_ws, size_t ws_size,
                              hipStream_t stream) {
  const float* p1 = (const float*)d_in[0];
  const float* p2 = (const float*)d_in[1];
  ushort* p1t = (ushort*)d_ws;
  ushort* p2t = p1t + (size_t)NN * DD;
  float* a2 = (float*)(p2t + (size_t)NN * DD);
  float* b2 = a2 + NN;
  float* c = b2 + NN;
  unsigned int* rowmax = (unsigned int*)(c + NN);
  float* sumpart = (float*)(rowmax + NN);

  ptl_prep<<<NN / 4, 256, 0, stream>>>(p1, p2, p1t, p2t, a2, b2, c,
                                       rowmax, sumpart);

  dim3 grid(GX, GY);  // (32, 16) = 512 blocks, 2 per CU
  ptl_mfma<<<grid, 512, 0, stream>>>(p1t, p2t, a2, b2, c, rowmax, sumpart);

  ptl_fin<<<1, 256, 0, stream>>>(rowmax, sumpart, (float*)d_out);
}